// Round 3
// baseline (378.226 us; speedup 1.0000x reference)
//
#include <hip/hip_runtime.h>
#include <hip/hip_bf16.h>

#define B_ 32
#define C_ 384
#define N_ 4096
#define M_ 64
#define R_ 16

typedef __attribute__((ext_vector_type(8))) short short8;
typedef __attribute__((ext_vector_type(4))) float f32x4;
typedef __attribute__((ext_vector_type(4))) int i32x4;

static __device__ __forceinline__ unsigned short f2bf(float f) {
    union { float f; unsigned u; } v; v.f = f;
    unsigned r = v.u + 0x7fffu + ((v.u >> 16) & 1u);   // RNE
    return (unsigned short)(r >> 16);
}

// =====================================================================
// Kernel 0 (unchanged): W2 = U*Vw (bf16 [64][384]) and b2 = U*Vb -> d_ws.
// =====================================================================
__global__ __launch_bounds__(256) void k_w2(
    const float* __restrict__ Vw, const float* __restrict__ Vb,
    const float* __restrict__ U, unsigned short* __restrict__ W2,
    float* __restrict__ b2)
{
    __shared__ float vws[16 * 384];
    __shared__ float vbs[16];
    const int t = threadIdx.x;

    #pragma unroll
    for (int j = 0; j < 6; ++j)
        ((float4*)vws)[t + j * 256] = ((const float4*)Vw)[t + j * 256];
    if (t < 16) vbs[t] = Vb[t];
    __syncthreads();

    const int m  = blockIdx.x * 8 + (t >> 5);
    const int cg = t & 31;
    float u[R_];
    #pragma unroll
    for (int r = 0; r < R_; ++r) u[r] = U[m * R_ + r];
    if (cg == 0) {
        float a = 0.f;
        #pragma unroll
        for (int r = 0; r < R_; ++r) a = fmaf(u[r], vbs[r], a);
        b2[m] = a;
    }
    #pragma unroll
    for (int j = 0; j < 6; ++j) {
        const int c = cg * 2 + j * 64;
        float a0 = 0.f, a1 = 0.f;
        #pragma unroll
        for (int r = 0; r < R_; ++r) {
            float2 vv = *(const float2*)(vws + r * C_ + c);
            a0 = fmaf(u[r], vv.x, a0);
            a1 = fmaf(u[r], vv.y, a1);
        }
        unsigned pk = (unsigned)f2bf(a0) | ((unsigned)f2bf(a1) << 16);
        *(unsigned*)&W2[m * C_ + c] = pk;
    }
}

// =====================================================================
// Fused kernel rev3: 2 blocks/CU.
//  n-subtile 64, n-range 256/block -> grid 32x16 = 512 blocks (2/CU).
//  LDS 77.8 KB: xcn[384][64] 48K + xts dbuf 2x[64][72] 18K + slds 8K + wred 2K.
//  Register diet for __launch_bounds__(512,4): W2 A-frags reloaded per
//  chunk from L2 (48KB, hot); xv ring depth-1 (16 regs).
//  1 barrier/chunk (disjoint chunk regions + xts dbuf); 9 barriers/subtile.
// =====================================================================
__global__ __launch_bounds__(512, 4) void k_fused(
    const float* __restrict__ x, const unsigned short* __restrict__ W2,
    const float* __restrict__ b2g, float* __restrict__ S, float* __restrict__ T)
{
    __shared__ unsigned short xcn[C_ * 64];      // [c][64n] bf16, XOR-swizzled
    __shared__ unsigned short xts[2][64][72];    // [n][64c +pad] bf16, dbuf
    __shared__ unsigned short slds[M_ * 64];     // [m][64n] bf16, XOR-swizzled
    __shared__ float wred[2][4][64];             // softmax cross-wave max/sum

    const int t    = threadIdx.x;
    const int lane = t & 63;
    const int col  = lane & 15;
    const int q    = lane >> 4;
    const int l31  = lane & 31;
    const int l5   = lane >> 5;
    const int w    = t >> 6;
    const int g    = w >> 1;      // logits m-group (16 m)
    const int h    = w & 1;       // logits n-half (32 n)

    const int b  = blockIdx.x >> 4;
    const int nq = blockIdx.x & 15;

    float bias[4];
    #pragma unroll
    for (int r = 0; r < 4; ++r) bias[r] = b2g[g * 16 + q * 4 + r];

    // Pooling accumulators: c = w*48 + ci*16 + (q*4+r), m = mt*16 + col.
    f32x4 acc2[3][4];
    #pragma unroll
    for (int ci = 0; ci < 3; ++ci)
        #pragma unroll
        for (int mt = 0; mt < 4; ++mt) acc2[ci][mt] = (f32x4){0.f, 0.f, 0.f, 0.f};

    const float* xb = x + (size_t)b * C_ * N_ + nq * 256 + 2 * l31;

    float2 xv[2][4];   // ring: per chunk each lane holds 4 c-rows x (n,n+1)

    auto ISSUE = [&](float2 (&dst)[4], int subp, int kcp) {
        const float* xp = xb + (size_t)(kcp * 64 + w * 8 + l5 * 4) * N_ + subp * 64;
        #pragma unroll
        for (int j = 0; j < 4; ++j)
            dst[j] = *(const float2*)(xp + (size_t)j * N_);
    };

    auto CONVERT = [&](float2 (&v)[4], int kcp, int buf) {
        unsigned short bx[4], by[4];
        #pragma unroll
        for (int j = 0; j < 4; ++j) { bx[j] = f2bf(v[j].x); by[j] = f2bf(v[j].y); }
        // xcn[c][n]: b32 packed (n,n+1); rows swizzled by (c&7)<<4
        #pragma unroll
        for (int j = 0; j < 4; ++j) {
            int c = kcp * 64 + w * 8 + l5 * 4 + j;
            unsigned pk = (unsigned)bx[j] | ((unsigned)by[j] << 16);
            *(unsigned*)((char*)xcn + c * 128 + ((4 * l31) ^ ((c & 7) << 4))) = pk;
        }
        // xts[buf][n][c]: b64 of 4 consecutive c at rows n, n+1
        int cl = w * 8 + l5 * 4;
        int2 pa, pb;
        pa.x = (int)((unsigned)bx[0] | ((unsigned)bx[1] << 16));
        pa.y = (int)((unsigned)bx[2] | ((unsigned)bx[3] << 16));
        pb.x = (int)((unsigned)by[0] | ((unsigned)by[1] << 16));
        pb.y = (int)((unsigned)by[2] | ((unsigned)by[3] << 16));
        *(int2*)&xts[buf][2 * l31][cl]     = pa;
        *(int2*)&xts[buf][2 * l31 + 1][cl] = pb;
    };

    ISSUE(xv[0], 0, 0);

    for (int sub = 0; sub < 4; ++sub) {
        f32x4 acc1[2];
        acc1[0] = (f32x4){0.f, 0.f, 0.f, 0.f};
        acc1[1] = (f32x4){0.f, 0.f, 0.f, 0.f};

        #pragma unroll
        for (int kc = 0; kc < 6; ++kc) {
            // refill ring one chunk ahead
            if (kc < 5)       ISSUE(xv[(kc + 1) & 1], sub, kc + 1);
            else if (sub < 3) ISSUE(xv[0], sub + 1, 0);

            CONVERT(xv[kc & 1], kc, kc & 1);
            __syncthreads();   // chunk kc published; prev chunk reads done (dbuf)

            // W2 A-frags for this chunk (L2-hot global reads)
            const unsigned short* wp = W2 + (g * 16 + col) * C_ + kc * 64 + q * 8;
            short8 af0 = *(const short8*)(wp);
            short8 af1 = *(const short8*)(wp + 32);

            #pragma unroll
            for (int ks = 0; ks < 2; ++ks) {
                short8 bfr[2];
                #pragma unroll
                for (int nt = 0; nt < 2; ++nt)
                    bfr[nt] = *(const short8*)&xts[kc & 1][h * 32 + nt * 16 + col][ks * 32 + q * 8];
                #pragma unroll
                for (int nt = 0; nt < 2; ++nt)
                    acc1[nt] = __builtin_amdgcn_mfma_f32_16x16x32_bf16(
                        ks ? af1 : af0, bfr[nt], acc1[nt], 0, 0, 0);
            }
        }

        // ---- one-pass softmax over m = 64 (4 m-group waves exchange) ----
        float mxl[2], scl[2];
        #pragma unroll
        for (int nt = 0; nt < 2; ++nt) {
            float mx = -3.4e38f;
            #pragma unroll
            for (int r = 0; r < 4; ++r) {
                float vv = acc1[nt][r] + bias[r];
                acc1[nt][r] = vv;
                mx = fmaxf(mx, vv);
            }
            mx = fmaxf(mx, __shfl_xor(mx, 16, 64));
            mx = fmaxf(mx, __shfl_xor(mx, 32, 64));
            float s = 0.f;
            #pragma unroll
            for (int r = 0; r < 4; ++r) {
                float e = __expf(acc1[nt][r] - mx);
                acc1[nt][r] = e;
                s += e;
            }
            s += __shfl_xor(s, 16, 64);
            s += __shfl_xor(s, 32, 64);
            mxl[nt] = mx;
            if (q == 0) {
                int n = h * 32 + nt * 16 + col;
                wred[0][g][n] = mx;
                wred[1][g][n] = s;
            }
        }
        __syncthreads();

        #pragma unroll
        for (int nt = 0; nt < 2; ++nt) {
            int n = h * 32 + nt * 16 + col;
            float m0 = wred[0][0][n], m1 = wred[0][1][n];
            float m2 = wred[0][2][n], m3 = wred[0][3][n];
            float M  = fmaxf(fmaxf(m0, m1), fmaxf(m2, m3));
            float tot = wred[1][0][n] * __expf(m0 - M) + wred[1][1][n] * __expf(m1 - M)
                      + wred[1][2][n] * __expf(m2 - M) + wred[1][3][n] * __expf(m3 - M);
            scl[nt] = __expf(mxl[nt] - M) / tot;
        }

        // ---- write S (f32) + slds (bf16, swizzled) ----
        float* Sp = S + (size_t)(b * M_ + g * 16 + q * 4) * N_ + nq * 256 + sub * 64;
        #pragma unroll
        for (int nt = 0; nt < 2; ++nt) {
            int n = h * 32 + nt * 16 + col;
            #pragma unroll
            for (int r = 0; r < 4; ++r) {
                float p = acc1[nt][r] * scl[nt];
                Sp[(size_t)r * N_ + n] = p;
                int m = g * 16 + q * 4 + r;
                *(unsigned short*)((char*)slds + m * 128 + ((2 * n) ^ ((m & 7) << 4))) = f2bf(p);
            }
        }
        __syncthreads();

        // ---- pooling GEMM: acc2[c][m] += sum_n xcn[c][n] * slds[m][n] ----
        #pragma unroll
        for (int ks = 0; ks < 2; ++ks) {
            short8 a2[3], bsf[4];
            #pragma unroll
            for (int ci = 0; ci < 3; ++ci) {
                int c = w * 48 + ci * 16 + col;
                a2[ci] = *(const short8*)((char*)xcn + c * 128 +
                                          ((ks * 64 + q * 16) ^ ((c & 7) << 4)));
            }
            #pragma unroll
            for (int mt = 0; mt < 4; ++mt) {
                int m = mt * 16 + col;
                bsf[mt] = *(const short8*)((char*)slds + m * 128 +
                                           ((ks * 64 + q * 16) ^ ((m & 7) << 4)));
            }
            #pragma unroll
            for (int ci = 0; ci < 3; ++ci)
                #pragma unroll
                for (int mt = 0; mt < 4; ++mt)
                    acc2[ci][mt] = __builtin_amdgcn_mfma_f32_16x16x32_bf16(
                        a2[ci], bsf[mt], acc2[ci][mt], 0, 0, 0);
        }
        __syncthreads();   // xcn/slds reads done before next subtile overwrites
    }

    // ---- epilogue: one atomicAdd pass ----
    float* Tb = T + (size_t)b * C_ * M_;
    #pragma unroll
    for (int ci = 0; ci < 3; ++ci) {
        int c = w * 48 + ci * 16 + q * 4;
        #pragma unroll
        for (int mt = 0; mt < 4; ++mt)
            #pragma unroll
            for (int r = 0; r < 4; ++r)
                atomicAdd(&Tb[(size_t)(c + r) * M_ + mt * 16 + col], acc2[ci][mt][r]);
    }
}

extern "C" void kernel_launch(void* const* d_in, const int* in_sizes, int n_in,
                              void* d_out, int out_size, void* d_ws, size_t ws_size,
                              hipStream_t stream) {
    const float* x  = (const float*)d_in[0];
    const float* Vw = (const float*)d_in[1];
    const float* Vb = (const float*)d_in[2];
    const float* U  = (const float*)d_in[3];
    float* T = (float*)d_out;                               // [B,C,M]
    float* S = (float*)d_out + (size_t)B_ * C_ * M_;        // [B,M,N]

    unsigned short* W2 = (unsigned short*)d_ws;             // [64][384] bf16
    float* b2 = (float*)((char*)d_ws + 64 * 384 * 2);       // [64] f32

    hipMemsetAsync(T, 0, (size_t)B_ * C_ * M_ * sizeof(float), stream);
    k_w2<<<dim3(8), dim3(256), 0, stream>>>(Vw, Vb, U, W2, b2);
    k_fused<<<dim3(512), dim3(512), 0, stream>>>(x, W2, b2, S, T);
}

// Round 4
// 327.083 us; speedup vs baseline: 1.1564x; 1.1564x over previous
//
#include <hip/hip_runtime.h>
#include <hip/hip_bf16.h>

#define B_ 32
#define C_ 384
#define N_ 4096
#define M_ 64
#define R_ 16

typedef __attribute__((ext_vector_type(8))) short short8;
typedef __attribute__((ext_vector_type(4))) float f32x4;
typedef __attribute__((ext_vector_type(4))) int i32x4;

static __device__ __forceinline__ unsigned short f2bf(float f) {
    union { float f; unsigned u; } v; v.f = f;
    unsigned r = v.u + 0x7fffu + ((v.u >> 16) & 1u);   // RNE
    return (unsigned short)(r >> 16);
}

// =====================================================================
// Kernel 0 (unchanged): W2 = U*Vw (bf16 [64][384]) and b2 = U*Vb -> d_ws.
// =====================================================================
__global__ __launch_bounds__(256) void k_w2(
    const float* __restrict__ Vw, const float* __restrict__ Vb,
    const float* __restrict__ U, unsigned short* __restrict__ W2,
    float* __restrict__ b2)
{
    __shared__ float vws[16 * 384];
    __shared__ float vbs[16];
    const int t = threadIdx.x;

    #pragma unroll
    for (int j = 0; j < 6; ++j)
        ((float4*)vws)[t + j * 256] = ((const float4*)Vw)[t + j * 256];
    if (t < 16) vbs[t] = Vb[t];
    __syncthreads();

    const int m  = blockIdx.x * 8 + (t >> 5);
    const int cg = t & 31;
    float u[R_];
    #pragma unroll
    for (int r = 0; r < R_; ++r) u[r] = U[m * R_ + r];
    if (cg == 0) {
        float a = 0.f;
        #pragma unroll
        for (int r = 0; r < R_; ++r) a = fmaf(u[r], vbs[r], a);
        b2[m] = a;
    }
    #pragma unroll
    for (int j = 0; j < 6; ++j) {
        const int c = cg * 2 + j * 64;
        float a0 = 0.f, a1 = 0.f;
        #pragma unroll
        for (int r = 0; r < R_; ++r) {
            float2 vv = *(const float2*)(vws + r * C_ + c);
            a0 = fmaf(u[r], vv.x, a0);
            a1 = fmaf(u[r], vv.y, a1);
        }
        unsigned pk = (unsigned)f2bf(a0) | ((unsigned)f2bf(a1) << 16);
        *(unsigned*)&W2[m * C_ + c] = pk;
    }
}

// =====================================================================
// Fused kernel rev4: 2 blocks/CU, spill-free.
//  - __launch_bounds__(512, 2): this toolchain's 2nd arg = min BLOCKS/CU
//    (R2/R3 evidence: VGPR cap 128/64) -> cap 128, no spills.
//  - xts pad 68 shorts (34 words, mod32=2 -> bank-optimal b64 writes;
//    the 72 pad was an 8-way conflict, 3.9M SQ_LDS_BANK_CONFLICT).
//  - W2 A-frags in a 2-deep register ring, prefetched one chunk ahead.
//  LDS 77.3 KB: xcn[384][64] 48K + xts 2x[64][68] 17.4K + slds 8K + wred 2K.
// =====================================================================
__global__ __launch_bounds__(512, 2) void k_fused(
    const float* __restrict__ x, const unsigned short* __restrict__ W2,
    const float* __restrict__ b2g, float* __restrict__ S, float* __restrict__ T)
{
    __shared__ unsigned short xcn[C_ * 64];      // [c][64n] bf16, XOR-swizzled
    __shared__ unsigned short xts[2][64][68];    // [n][64c +4 pad] bf16, dbuf
    __shared__ unsigned short slds[M_ * 64];     // [m][64n] bf16, XOR-swizzled
    __shared__ float wred[2][4][64];             // softmax cross-wave max/sum

    const int t    = threadIdx.x;
    const int lane = t & 63;
    const int col  = lane & 15;
    const int q    = lane >> 4;
    const int l31  = lane & 31;
    const int l5   = lane >> 5;
    const int w    = t >> 6;
    const int g    = w >> 1;      // logits m-group (16 m)
    const int h    = w & 1;       // logits n-half (32 n)

    const int b  = blockIdx.x >> 4;
    const int nq = blockIdx.x & 15;

    float bias[4];
    #pragma unroll
    for (int r = 0; r < 4; ++r) bias[r] = b2g[g * 16 + q * 4 + r];

    // Pooling accumulators: c = w*48 + ci*16 + (q*4+r), m = mt*16 + col.
    f32x4 acc2[3][4];
    #pragma unroll
    for (int ci = 0; ci < 3; ++ci)
        #pragma unroll
        for (int mt = 0; mt < 4; ++mt) acc2[ci][mt] = (f32x4){0.f, 0.f, 0.f, 0.f};

    const float* xb = x + (size_t)b * C_ * N_ + nq * 256 + 2 * l31;
    const unsigned short* wrow = W2 + (g * 16 + col) * C_ + q * 8;

    float2 xv[2][4];     // x chunk ring: 4 c-rows x (n,n+1) per lane
    short8 afr[2][2];    // W2 A-frag ring: [ring][ks]

    auto ISSUE = [&](float2 (&dst)[4], int subp, int kcp) {
        const float* xp = xb + (size_t)(kcp * 64 + w * 8 + l5 * 4) * N_ + subp * 64;
        #pragma unroll
        for (int j = 0; j < 4; ++j)
            dst[j] = *(const float2*)(xp + (size_t)j * N_);
    };

    auto WLOAD = [&](short8 (&dst)[2], int kcp) {
        dst[0] = *(const short8*)(wrow + kcp * 64);
        dst[1] = *(const short8*)(wrow + kcp * 64 + 32);
    };

    auto CONVERT = [&](float2 (&v)[4], int kcp, int buf) {
        unsigned short bx[4], by[4];
        #pragma unroll
        for (int j = 0; j < 4; ++j) { bx[j] = f2bf(v[j].x); by[j] = f2bf(v[j].y); }
        // xcn[c][n]: b32 packed (n,n+1); byte-swizzle ((c&7)<<4) -> ~2-way
        #pragma unroll
        for (int j = 0; j < 4; ++j) {
            int c = kcp * 64 + w * 8 + l5 * 4 + j;
            unsigned pk = (unsigned)bx[j] | ((unsigned)by[j] << 16);
            *(unsigned*)((char*)xcn + c * 128 + ((4 * l31) ^ ((c & 7) << 4))) = pk;
        }
        // xts[buf][n][c]: b64 of 4 consecutive c at rows 2*l31, 2*l31+1
        int cl = w * 8 + l5 * 4;
        int2 pa, pb;
        pa.x = (int)((unsigned)bx[0] | ((unsigned)bx[1] << 16));
        pa.y = (int)((unsigned)bx[2] | ((unsigned)bx[3] << 16));
        pb.x = (int)((unsigned)by[0] | ((unsigned)by[1] << 16));
        pb.y = (int)((unsigned)by[2] | ((unsigned)by[3] << 16));
        *(int2*)&xts[buf][2 * l31][cl]     = pa;
        *(int2*)&xts[buf][2 * l31 + 1][cl] = pb;
    };

    ISSUE(xv[0], 0, 0);
    WLOAD(afr[0], 0);

    for (int sub = 0; sub < 4; ++sub) {
        f32x4 acc1[2];
        acc1[0] = (f32x4){0.f, 0.f, 0.f, 0.f};
        acc1[1] = (f32x4){0.f, 0.f, 0.f, 0.f};

        #pragma unroll
        for (int kc = 0; kc < 6; ++kc) {
            // refill rings one chunk ahead
            if (kc < 5) {
                ISSUE(xv[(kc + 1) & 1], sub, kc + 1);
                WLOAD(afr[(kc + 1) & 1], kc + 1);
            } else {
                if (sub < 3) ISSUE(xv[0], sub + 1, 0);
                WLOAD(afr[0], 0);
            }

            CONVERT(xv[kc & 1], kc, kc & 1);
            __syncthreads();   // chunk kc published; prev chunk reads done (dbuf)

            #pragma unroll
            for (int ks = 0; ks < 2; ++ks) {
                short8 bfr[2];
                #pragma unroll
                for (int nt = 0; nt < 2; ++nt)
                    bfr[nt] = *(const short8*)&xts[kc & 1][h * 32 + nt * 16 + col][ks * 32 + q * 8];
                #pragma unroll
                for (int nt = 0; nt < 2; ++nt)
                    acc1[nt] = __builtin_amdgcn_mfma_f32_16x16x32_bf16(
                        afr[kc & 1][ks], bfr[nt], acc1[nt], 0, 0, 0);
            }
        }

        // ---- one-pass softmax over m = 64 (4 m-group waves exchange) ----
        float mxl[2], scl[2];
        #pragma unroll
        for (int nt = 0; nt < 2; ++nt) {
            float mx = -3.4e38f;
            #pragma unroll
            for (int r = 0; r < 4; ++r) {
                float vv = acc1[nt][r] + bias[r];
                acc1[nt][r] = vv;
                mx = fmaxf(mx, vv);
            }
            mx = fmaxf(mx, __shfl_xor(mx, 16, 64));
            mx = fmaxf(mx, __shfl_xor(mx, 32, 64));
            float s = 0.f;
            #pragma unroll
            for (int r = 0; r < 4; ++r) {
                float e = __expf(acc1[nt][r] - mx);
                acc1[nt][r] = e;
                s += e;
            }
            s += __shfl_xor(s, 16, 64);
            s += __shfl_xor(s, 32, 64);
            mxl[nt] = mx;
            if (q == 0) {
                int n = h * 32 + nt * 16 + col;
                wred[0][g][n] = mx;
                wred[1][g][n] = s;
            }
        }
        __syncthreads();

        #pragma unroll
        for (int nt = 0; nt < 2; ++nt) {
            int n = h * 32 + nt * 16 + col;
            float m0 = wred[0][0][n], m1 = wred[0][1][n];
            float m2 = wred[0][2][n], m3 = wred[0][3][n];
            float M  = fmaxf(fmaxf(m0, m1), fmaxf(m2, m3));
            float tot = wred[1][0][n] * __expf(m0 - M) + wred[1][1][n] * __expf(m1 - M)
                      + wred[1][2][n] * __expf(m2 - M) + wred[1][3][n] * __expf(m3 - M);
            scl[nt] = __expf(mxl[nt] - M) / tot;
        }

        // ---- write S (f32) + slds (bf16, swizzled) ----
        float* Sp = S + (size_t)(b * M_ + g * 16 + q * 4) * N_ + nq * 256 + sub * 64;
        #pragma unroll
        for (int nt = 0; nt < 2; ++nt) {
            int n = h * 32 + nt * 16 + col;
            #pragma unroll
            for (int r = 0; r < 4; ++r) {
                float p = acc1[nt][r] * scl[nt];
                Sp[(size_t)r * N_ + n] = p;
                int m = g * 16 + q * 4 + r;
                *(unsigned short*)((char*)slds + m * 128 + ((2 * n) ^ ((m & 7) << 4))) = f2bf(p);
            }
        }
        __syncthreads();

        // ---- pooling GEMM: acc2[c][m] += sum_n xcn[c][n] * slds[m][n] ----
        #pragma unroll
        for (int ks = 0; ks < 2; ++ks) {
            short8 a2[3], bsf[4];
            #pragma unroll
            for (int ci = 0; ci < 3; ++ci) {
                int c = w * 48 + ci * 16 + col;
                a2[ci] = *(const short8*)((char*)xcn + c * 128 +
                                          ((ks * 64 + q * 16) ^ ((c & 7) << 4)));
            }
            #pragma unroll
            for (int mt = 0; mt < 4; ++mt) {
                int m = mt * 16 + col;
                bsf[mt] = *(const short8*)((char*)slds + m * 128 +
                                           ((ks * 64 + q * 16) ^ ((m & 7) << 4)));
            }
            #pragma unroll
            for (int ci = 0; ci < 3; ++ci)
                #pragma unroll
                for (int mt = 0; mt < 4; ++mt)
                    acc2[ci][mt] = __builtin_amdgcn_mfma_f32_16x16x32_bf16(
                        a2[ci], bsf[mt], acc2[ci][mt], 0, 0, 0);
        }
        __syncthreads();   // xcn/slds reads done before next subtile overwrites
    }

    // ---- epilogue: one atomicAdd pass ----
    float* Tb = T + (size_t)b * C_ * M_;
    #pragma unroll
    for (int ci = 0; ci < 3; ++ci) {
        int c = w * 48 + ci * 16 + q * 4;
        #pragma unroll
        for (int mt = 0; mt < 4; ++mt)
            #pragma unroll
            for (int r = 0; r < 4; ++r)
                atomicAdd(&Tb[(size_t)(c + r) * M_ + mt * 16 + col], acc2[ci][mt][r]);
    }
}

extern "C" void kernel_launch(void* const* d_in, const int* in_sizes, int n_in,
                              void* d_out, int out_size, void* d_ws, size_t ws_size,
                              hipStream_t stream) {
    const float* x  = (const float*)d_in[0];
    const float* Vw = (const float*)d_in[1];
    const float* Vb = (const float*)d_in[2];
    const float* U  = (const float*)d_in[3];
    float* T = (float*)d_out;                               // [B,C,M]
    float* S = (float*)d_out + (size_t)B_ * C_ * M_;        // [B,M,N]

    unsigned short* W2 = (unsigned short*)d_ws;             // [64][384] bf16
    float* b2 = (float*)((char*)d_ws + 64 * 384 * 2);       // [64] f32

    hipMemsetAsync(T, 0, (size_t)B_ * C_ * M_ * sizeof(float), stream);
    k_w2<<<dim3(8), dim3(256), 0, stream>>>(Vw, Vb, U, W2, b2);
    k_fused<<<dim3(512), dim3(512), 0, stream>>>(x, W2, b2, S, T);
}

// Round 5
// 315.229 us; speedup vs baseline: 1.1998x; 1.0376x over previous
//
#include <hip/hip_runtime.h>
#include <hip/hip_bf16.h>

#define B_ 32
#define C_ 384
#define N_ 4096
#define M_ 64
#define R_ 16

typedef __attribute__((ext_vector_type(8))) short short8;
typedef __attribute__((ext_vector_type(4))) float f32x4;
typedef __attribute__((ext_vector_type(4))) int i32x4;

static __device__ __forceinline__ unsigned short f2bf(float f) {
    union { float f; unsigned u; } v; v.f = f;
    unsigned r = v.u + 0x7fffu + ((v.u >> 16) & 1u);   // RNE
    return (unsigned short)(r >> 16);
}

// packed f32x2 -> bf16x2 (v_cvt_pk_bf16_f32, RNE); lo -> bits[15:0]
static __device__ __forceinline__ unsigned pk2(float lo, float hi) {
    __hip_bfloat162 t = __float22bfloat162_rn(float2{lo, hi});
    return *reinterpret_cast<unsigned*>(&t);
}

// =====================================================================
// Kernel 0 (unchanged): W2 = U*Vw (bf16 [64][384]) and b2 = U*Vb -> d_ws.
// =====================================================================
__global__ __launch_bounds__(256) void k_w2(
    const float* __restrict__ Vw, const float* __restrict__ Vb,
    const float* __restrict__ U, unsigned short* __restrict__ W2,
    float* __restrict__ b2)
{
    __shared__ float vws[16 * 384];
    __shared__ float vbs[16];
    const int t = threadIdx.x;

    #pragma unroll
    for (int j = 0; j < 6; ++j)
        ((float4*)vws)[t + j * 256] = ((const float4*)Vw)[t + j * 256];
    if (t < 16) vbs[t] = Vb[t];
    __syncthreads();

    const int m  = blockIdx.x * 8 + (t >> 5);
    const int cg = t & 31;
    float u[R_];
    #pragma unroll
    for (int r = 0; r < R_; ++r) u[r] = U[m * R_ + r];
    if (cg == 0) {
        float a = 0.f;
        #pragma unroll
        for (int r = 0; r < R_; ++r) a = fmaf(u[r], vbs[r], a);
        b2[m] = a;
    }
    #pragma unroll
    for (int j = 0; j < 6; ++j) {
        const int c = cg * 2 + j * 64;
        float a0 = 0.f, a1 = 0.f;
        #pragma unroll
        for (int r = 0; r < R_; ++r) {
            float2 vv = *(const float2*)(vws + r * C_ + c);
            a0 = fmaf(u[r], vv.x, a0);
            a1 = fmaf(u[r], vv.y, a1);
        }
        unsigned pk = (unsigned)f2bf(a0) | ((unsigned)f2bf(a1) << 16);
        *(unsigned*)&W2[m * C_ + c] = pk;
    }
}

// =====================================================================
// Fused kernel rev5: 2 blocks/CU + depth-3 prefetch + no atomic tail.
//  - __launch_bounds__(512, 2): 2nd arg = min BLOCKS/CU on this toolchain
//    (R2/R3/R4 evidence: VGPR caps 128/64/128) -> 128-reg cap.
//  - x ring depth 3: chunk consumed at kc issued at kc-3 (~900+ cy ahead);
//    next-subtile chunks 0..2 issued at kc=3,4,5 (fly over softmax/GEMM2).
//  - packed bf16 cvt (v_cvt_pk_bf16_f32) instead of scalar bit-twiddle.
//  - epilogue: plain stores of partial T to ws; k_reduce sums 16 partials.
//  LDS 76800: xcn[384][64] 48K + xts 2x[64][68] 17K + slds 8K + wred 2K.
// =====================================================================
__global__ __launch_bounds__(512, 2) void k_fused(
    const float* __restrict__ x, const unsigned short* __restrict__ W2,
    const float* __restrict__ b2g, float* __restrict__ S, float* __restrict__ Tp)
{
    __shared__ unsigned short xcn[C_ * 64];      // [c][64n] bf16, XOR-swizzled
    __shared__ unsigned short xts[2][64][68];    // [n][64c +4 pad] bf16, dbuf
    __shared__ unsigned short slds[M_ * 64];     // [m][64n] bf16, XOR-swizzled
    __shared__ float wred[2][4][64];             // softmax cross-wave max/sum

    const int t    = threadIdx.x;
    const int lane = t & 63;
    const int col  = lane & 15;
    const int q    = lane >> 4;
    const int l31  = lane & 31;
    const int l5   = lane >> 5;
    const int w    = t >> 6;
    const int g    = w >> 1;      // logits m-group (16 m)
    const int h    = w & 1;       // logits n-half (32 n)

    const int b  = blockIdx.x >> 4;
    const int nq = blockIdx.x & 15;

    float bias[4];
    #pragma unroll
    for (int r = 0; r < 4; ++r) bias[r] = b2g[g * 16 + q * 4 + r];

    // Pooling accumulators: c = w*48 + ci*16 + (q*4+r), m = mt*16 + col.
    f32x4 acc2[3][4];
    #pragma unroll
    for (int ci = 0; ci < 3; ++ci)
        #pragma unroll
        for (int mt = 0; mt < 4; ++mt) acc2[ci][mt] = (f32x4){0.f, 0.f, 0.f, 0.f};

    const float* xb = x + (size_t)b * C_ * N_ + nq * 256 + 2 * l31;
    const unsigned short* wrow = W2 + (g * 16 + col) * C_ + q * 8;

    float2 xv[3][4];     // depth-3 x chunk ring: 4 c-rows x (n,n+1) per lane
    short8 afr[2][2];    // W2 A-frag ring: [ring][ks]

    auto ISSUE = [&](float2 (&dst)[4], int subp, int kcp) {
        const float* xp = xb + (size_t)(kcp * 64 + w * 8 + l5 * 4) * N_ + subp * 64;
        #pragma unroll
        for (int j = 0; j < 4; ++j)
            dst[j] = *(const float2*)(xp + (size_t)j * N_);
    };

    auto WLOAD = [&](short8 (&dst)[2], int kcp) {
        dst[0] = *(const short8*)(wrow + kcp * 64);
        dst[1] = *(const short8*)(wrow + kcp * 64 + 32);
    };

    auto CONVERT = [&](float2 (&v)[4], int kcp, int buf) {
        // xcn[c][n]: b32 packed (n,n+1); byte-swizzle ((c&7)<<4)
        #pragma unroll
        for (int j = 0; j < 4; ++j) {
            int c = kcp * 64 + w * 8 + l5 * 4 + j;
            *(unsigned*)((char*)xcn + c * 128 + ((4 * l31) ^ ((c & 7) << 4))) =
                pk2(v[j].x, v[j].y);
        }
        // xts[buf][n][c]: b64 of 4 consecutive c at rows 2*l31, 2*l31+1
        int cl = w * 8 + l5 * 4;
        int2 pa, pb;
        pa.x = (int)pk2(v[0].x, v[1].x);
        pa.y = (int)pk2(v[2].x, v[3].x);
        pb.x = (int)pk2(v[0].y, v[1].y);
        pb.y = (int)pk2(v[2].y, v[3].y);
        *(int2*)&xts[buf][2 * l31][cl]     = pa;
        *(int2*)&xts[buf][2 * l31 + 1][cl] = pb;
    };

    ISSUE(xv[0], 0, 0);
    ISSUE(xv[1], 0, 1);
    ISSUE(xv[2], 0, 2);
    WLOAD(afr[0], 0);

    for (int sub = 0; sub < 4; ++sub) {
        f32x4 acc1[2];
        acc1[0] = (f32x4){0.f, 0.f, 0.f, 0.f};
        acc1[1] = (f32x4){0.f, 0.f, 0.f, 0.f};

        #pragma unroll
        for (int kc = 0; kc < 6; ++kc) {
            CONVERT(xv[kc % 3], kc, kc & 1);
            // refill ring slot with chunk kc+3 (local or next-subtile)
            const int nk = kc + 3;
            if (nk < 6)       ISSUE(xv[kc % 3], sub, nk);
            else if (sub < 3) ISSUE(xv[kc % 3], sub + 1, nk - 6);
            // W2 frag ring one chunk ahead (L2-hot)
            if (kc < 5) WLOAD(afr[(kc + 1) & 1], kc + 1);
            else        WLOAD(afr[0], 0);

            __syncthreads();   // chunk kc published; prev buf reads done (dbuf)

            #pragma unroll
            for (int ks = 0; ks < 2; ++ks) {
                short8 bfr[2];
                #pragma unroll
                for (int nt = 0; nt < 2; ++nt)
                    bfr[nt] = *(const short8*)&xts[kc & 1][h * 32 + nt * 16 + col][ks * 32 + q * 8];
                #pragma unroll
                for (int nt = 0; nt < 2; ++nt)
                    acc1[nt] = __builtin_amdgcn_mfma_f32_16x16x32_bf16(
                        afr[kc & 1][ks], bfr[nt], acc1[nt], 0, 0, 0);
            }
        }

        // ---- one-pass softmax over m = 64 (4 m-group waves exchange) ----
        float mxl[2], scl[2];
        #pragma unroll
        for (int nt = 0; nt < 2; ++nt) {
            float mx = -3.4e38f;
            #pragma unroll
            for (int r = 0; r < 4; ++r) {
                float vv = acc1[nt][r] + bias[r];
                acc1[nt][r] = vv;
                mx = fmaxf(mx, vv);
            }
            mx = fmaxf(mx, __shfl_xor(mx, 16, 64));
            mx = fmaxf(mx, __shfl_xor(mx, 32, 64));
            float s = 0.f;
            #pragma unroll
            for (int r = 0; r < 4; ++r) {
                float e = __expf(acc1[nt][r] - mx);
                acc1[nt][r] = e;
                s += e;
            }
            s += __shfl_xor(s, 16, 64);
            s += __shfl_xor(s, 32, 64);
            mxl[nt] = mx;
            if (q == 0) {
                int n = h * 32 + nt * 16 + col;
                wred[0][g][n] = mx;
                wred[1][g][n] = s;
            }
        }
        __syncthreads();

        #pragma unroll
        for (int nt = 0; nt < 2; ++nt) {
            int n = h * 32 + nt * 16 + col;
            float m0 = wred[0][0][n], m1 = wred[0][1][n];
            float m2 = wred[0][2][n], m3 = wred[0][3][n];
            float M  = fmaxf(fmaxf(m0, m1), fmaxf(m2, m3));
            float tot = wred[1][0][n] * __expf(m0 - M) + wred[1][1][n] * __expf(m1 - M)
                      + wred[1][2][n] * __expf(m2 - M) + wred[1][3][n] * __expf(m3 - M);
            scl[nt] = __expf(mxl[nt] - M) / tot;
        }

        // ---- write S (f32) + slds (bf16, swizzled) ----
        float* Sp = S + (size_t)(b * M_ + g * 16 + q * 4) * N_ + nq * 256 + sub * 64;
        #pragma unroll
        for (int nt = 0; nt < 2; ++nt) {
            int n = h * 32 + nt * 16 + col;
            #pragma unroll
            for (int r = 0; r < 4; ++r) {
                float p = acc1[nt][r] * scl[nt];
                Sp[(size_t)r * N_ + n] = p;
                int m = g * 16 + q * 4 + r;
                *(unsigned short*)((char*)slds + m * 128 + ((2 * n) ^ ((m & 7) << 4))) = f2bf(p);
            }
        }
        __syncthreads();

        // ---- pooling GEMM: acc2[c][m] += sum_n xcn[c][n] * slds[m][n] ----
        #pragma unroll
        for (int ks = 0; ks < 2; ++ks) {
            short8 a2[3], bsf[4];
            #pragma unroll
            for (int ci = 0; ci < 3; ++ci) {
                int c = w * 48 + ci * 16 + col;
                a2[ci] = *(const short8*)((char*)xcn + c * 128 +
                                          ((ks * 64 + q * 16) ^ ((c & 7) << 4)));
            }
            #pragma unroll
            for (int mt = 0; mt < 4; ++mt) {
                int m = mt * 16 + col;
                bsf[mt] = *(const short8*)((char*)slds + m * 128 +
                                           ((ks * 64 + q * 16) ^ ((m & 7) << 4)));
            }
            #pragma unroll
            for (int ci = 0; ci < 3; ++ci)
                #pragma unroll
                for (int mt = 0; mt < 4; ++mt)
                    acc2[ci][mt] = __builtin_amdgcn_mfma_f32_16x16x32_bf16(
                        a2[ci], bsf[mt], acc2[ci][mt], 0, 0, 0);
        }
        __syncthreads();   // xcn/slds reads done before next subtile overwrites
    }

    // ---- epilogue: plain stores of this block's partial T ----
    float* Tb = Tp + ((size_t)nq * B_ + b) * C_ * M_;
    #pragma unroll
    for (int ci = 0; ci < 3; ++ci) {
        int c = w * 48 + ci * 16 + q * 4;
        #pragma unroll
        for (int mt = 0; mt < 4; ++mt)
            #pragma unroll
            for (int r = 0; r < 4; ++r)
                Tb[(size_t)(c + r) * M_ + mt * 16 + col] = acc2[ci][mt][r];
    }
}

// =====================================================================
// Reduce: T[i] = sum_{nq<16} Tp[nq][i], vectorized f32x4. 768 blocks.
// =====================================================================
__global__ __launch_bounds__(256) void k_reduce(
    const float* __restrict__ Tp, float* __restrict__ T)
{
    const size_t SZ = (size_t)B_ * C_ * M_;   // 786432
    size_t i = (size_t)(blockIdx.x * 256 + threadIdx.x) * 4;
    f32x4 s = *(const f32x4*)&Tp[i];
    #pragma unroll
    for (int p = 1; p < 16; ++p) {
        f32x4 v = *(const f32x4*)&Tp[p * SZ + i];
        s.x += v.x; s.y += v.y; s.z += v.z; s.w += v.w;
    }
    *(f32x4*)&T[i] = s;
}

extern "C" void kernel_launch(void* const* d_in, const int* in_sizes, int n_in,
                              void* d_out, int out_size, void* d_ws, size_t ws_size,
                              hipStream_t stream) {
    const float* x  = (const float*)d_in[0];
    const float* Vw = (const float*)d_in[1];
    const float* Vb = (const float*)d_in[2];
    const float* U  = (const float*)d_in[3];
    float* T = (float*)d_out;                               // [B,C,M]
    float* S = (float*)d_out + (size_t)B_ * C_ * M_;        // [B,M,N]

    unsigned short* W2 = (unsigned short*)d_ws;             // [64][384] bf16
    float* b2 = (float*)((char*)d_ws + 64 * 384 * 2);       // [64] f32
    float* Tp = (float*)((char*)d_ws + (1 << 16));          // [16][B,C,M] f32

    k_w2<<<dim3(8), dim3(256), 0, stream>>>(Vw, Vb, U, W2, b2);
    k_fused<<<dim3(512), dim3(512), 0, stream>>>(x, W2, b2, S, Tp);
    k_reduce<<<dim3(768), dim3(256), 0, stream>>>(Tp, T);
}